// Round 6
// baseline (501.991 us; speedup 1.0000x reference)
//
#include <hip/hip_runtime.h>

// HTMM: C=32 states, L=4 fanout, M=128 symbols, DEPTH=7.
// Level starts: {0,1,5,21,85,341,1365,5461,21845}.
// SINGLE fused kernel, 257 blocks x 256 threads:
//   blocks 0..255 : one level-4 subtree each (85 nodes: root,4,16,64 leaves)
//   block  256    : top of tree (nodes 0..84), consumes level-4 betas,
//                   produces level-4 eps.
// Co-residency of all 257 blocks is REQUIRED (producer/consumer flags):
// __launch_bounds__(256,2) caps VGPR at 256 (>=2 waves/EU) and LDS is ~62 KB,
// so capacity is 2 blocks/CU x 256 CUs = 512 >= 257. Handoff via device-scope
// flags (MAGIC != 0xAA poison).

static constexpr int OFF_B4     = 0;      // level-4 betas  [s*32+i] (8192 f)
static constexpr int OFF_EPS4   = 8192;   // level-4 eps    [s*32+i] (8192 f)
static constexpr int OFF_ACC    = 16384;  // fp64 accumulator (2 f, 8B-aligned)
static constexpr int OFF_DONE   = 16386;  // int counter (init by top block)
static constexpr int OFF_FLAGB  = 16387;  // int flag: eps4 ready
static constexpr int OFF_FLAGSA = 16388;  // 256 int flags: level-4 beta ready
static constexpr int MAGIC      = 0x5CA1AB1E;

__device__ __forceinline__ float rsum32(float v) {
  v += __shfl_xor(v, 1);
  v += __shfl_xor(v, 2);
  v += __shfl_xor(v, 4);
  v += __shfl_xor(v, 8);
  v += __shfl_xor(v, 16);
  return v;
}
__device__ __forceinline__ float4 exp4(float4 v) {
  return make_float4(expf(v.x), expf(v.y), expf(v.z), expf(v.w));
}

// tb = sum_k Wr[k]*X[k], k=0..127; X read as uniform-address float4 (broadcast).
__device__ __forceinline__ float dot128(const float* Wr, const float* X) {
  float t0 = 0.f, t1 = 0.f, t2 = 0.f, t3 = 0.f;
#pragma unroll
  for (int j = 0; j < 32; ++j) {
    const float4 xv = *(const float4*)(X + j * 4);
    t0 = fmaf(Wr[j * 4 + 0], xv.x, t0);
    t1 = fmaf(Wr[j * 4 + 1], xv.y, t1);
    t2 = fmaf(Wr[j * 4 + 2], xv.z, t2);
    t3 = fmaf(Wr[j * 4 + 3], xv.w, t3);
  }
  return (t0 + t1) + (t2 + t3);
}

// w[l] = sum_i ASP[i,j=lane,l]*r[i] (Wr regs), u[l] = sum_i ALG[i,j=lane,l]*r[i].
__device__ __forceinline__ void wu128(const float* Wr, const float* ALG,
                                      const float* rb, int lane,
                                      float w[4], float u[4]) {
  w[0] = w[1] = w[2] = w[3] = 0.f;
  u[0] = u[1] = u[2] = u[3] = 0.f;
#pragma unroll
  for (int ii = 0; ii < 32; ii += 4) {
    const float4 rv = *(const float4*)(rb + ii);
#pragma unroll
    for (int di = 0; di < 4; ++di) {
      const int i = ii + di;
      const float rr = (di == 0) ? rv.x : (di == 1) ? rv.y : (di == 2) ? rv.z : rv.w;
      const float4 av = *(const float4*)(ALG + i * 128 + lane * 4);
      w[0] = fmaf(Wr[i * 4 + 0], rr, w[0]);
      u[0] = fmaf(av.x, rr, u[0]);
      w[1] = fmaf(Wr[i * 4 + 1], rr, w[1]);
      u[1] = fmaf(av.y, rr, u[1]);
      w[2] = fmaf(Wr[i * 4 + 2], rr, w[2]);
      u[2] = fmaf(av.z, rr, u[2]);
      w[3] = fmaf(Wr[i * 4 + 3], rr, w[3]);
      u[3] = fmaf(av.w, rr, u[3]);
    }
  }
}

__global__ __launch_bounds__(256, 2) void k_fused(const int* __restrict__ labels,
                                                  const float* __restrict__ A,
                                                  const float* __restrict__ B,
                                                  const float* __restrict__ Pi,
                                                  const float* __restrict__ SP,
                                                  float* __restrict__ ws,
                                                  float* __restrict__ out) {
  // LDS (floats):
  //  regW[4224]  : asp up-layout [i*132 + 4j+l]  -> later ALG down-layout [i*128+j*4+l]
  //  regB[4224]  : smB^T [m*33+i]                -> logged in place at transition
  //  sPt [132]   : smPi^T [l*33+i]               -> logged in place
  //  U   [5440]  : subtree: X7[0,2048) X6[2048,2560) X5[2560,2688) tbr[2688,3360)
  //                top:     bX3[0,2048) bX2[2048,2560) bX1[2560,2688)
  //                         bRoot[2688,2720) tbrT[2720,5440)
  //  r_buf[1024] : U1 staging (top) / r broadcast buffers (down, parity)
  __shared__ __align__(16) float regW[4224];
  __shared__ __align__(16) float regB[4224];
  __shared__ __align__(16) float sPt[132];
  __shared__ __align__(16) float U[5440];
  __shared__ __align__(16) float r_buf[1024];
  __shared__ int labs[341];
  const int t = threadIdx.x, lane = t & 31, grp = t >> 5;  // 8 groups
  const int s = blockIdx.x;
  const bool top = (s == 256);
  int* wsi = (int*)ws;
  const float4* A4 = (const float4*)A;
  const float4* B4 = (const float4*)B;

  // ---------- phase 1: softmax tables (per block, from raw inputs) ----------
  const float sv0 = SP[0], sv1 = SP[1], sv2 = SP[2], sv3 = SP[3];
  const float sp0 = expf(sv0), sp1 = expf(sv1), sp2 = expf(sv2), sp3 = expf(sv3);
  const float spsum = sp0 + sp1 + sp2 + sp3;
  const float spinv = 1.f / spsum;
  const float lss = logf(spsum);
  // A column sums: lane owns columns jl = 4*lane..4*lane+3 (j=lane, l=0..3)
  float4 c4 = make_float4(0.f, 0.f, 0.f, 0.f);
  for (int i = 0; i < 32; ++i) {
    const float4 e = exp4(A4[i * 32 + lane]);
    c4.x += e.x; c4.y += e.y; c4.z += e.z; c4.w += e.w;
  }
  const float4 inv4 = make_float4(sp0 * spinv / c4.x, sp1 * spinv / c4.y,
                                  sp2 * spinv / c4.z, sp3 * spinv / c4.w);
  const float4 sub4 = make_float4(logf(c4.x) - (sv0 - lss), logf(c4.y) - (sv1 - lss),
                                  logf(c4.z) - (sv2 - lss), logf(c4.w) - (sv3 - lss));
  // regW (asp, up layout, stride 132): group g writes rows g*4..g*4+3
#pragma unroll
  for (int k = 0; k < 4; ++k) {
    const int i = grp * 4 + k;
    const float4 e = exp4(A4[i * 32 + lane]);
    *(float4*)(regW + i * 132 + 4 * lane) =
        make_float4(e.x * inv4.x, e.y * inv4.y, e.z * inv4.z, e.w * inv4.w);
  }
  // regB: smB^T (stride 33)
#pragma unroll
  for (int rI = 0; rI < 4; ++rI) {
    const int i = grp + rI * 8;
    const float4 e = exp4(B4[i * 32 + lane]);
    const float sinv = 1.f / rsum32(e.x + e.y + e.z + e.w);
    regB[(4 * lane + 0) * 33 + i] = e.x * sinv;
    regB[(4 * lane + 1) * 33 + i] = e.y * sinv;
    regB[(4 * lane + 2) * 33 + i] = e.z * sinv;
    regB[(4 * lane + 3) * 33 + i] = e.w * sinv;
  }
  // sPt: smPi^T
  if (grp < 4) {
    const float e = expf(Pi[lane * 4 + grp]);
    sPt[grp * 33 + lane] = e / rsum32(e);
  }
  // labels
  if (top) {
    for (int idx = t; idx < 341; idx += 256) labs[idx] = labels[idx];
    if (t == 0) {
      *(double*)(ws + OFF_ACC) = 0.0;
      __hip_atomic_store(&wsi[OFF_DONE], 0, __ATOMIC_RELEASE, __HIP_MEMORY_SCOPE_AGENT);
    }
  } else if (t < 85) {
    int g;
    if (t == 0) g = 85 + s;
    else if (t < 5) g = 341 + s * 4 + (t - 1);
    else if (t < 21) g = 1365 + s * 16 + (t - 5);
    else g = 5461 + s * 64 + (t - 21);
    labs[t] = labels[g];
  }
  __syncthreads();
  // Wr, up orientation: lane = state i; Wr[4j+l] = ASP[i,j,l]
  float Wr[128];
#pragma unroll
  for (int j = 0; j < 32; ++j) {
    const float4 v = *(const float4*)(regW + lane * 132 + j * 4);
    Wr[4 * j] = v.x; Wr[4 * j + 1] = v.y; Wr[4 * j + 2] = v.z; Wr[4 * j + 3] = v.w;
  }

  // ---------- phase 2: up sweep ----------
  if (!top) {
    // S1: 64 leaves -> X7
    for (int q = grp; q < 64; q += 8) {
      const int lab = labs[21 + q], l = q & 3;
      float v = sPt[l * 33 + lane] * regB[lab * 33 + lane];
      v /= rsum32(v);
      U[(q >> 2) * 128 + lane * 4 + l] = v;
    }
    __syncthreads();
    // S2: 16 level-6 parents
    for (int p = grp; p < 16; p += 8) {
      const float tb = dot128(Wr, U + p * 128);
      const int lab = labs[5 + p];
      float bl = tb * regB[lab * 33 + lane];
      bl /= rsum32(bl);
      U[2688 + (5 + p) * 32 + lane] = tb;
      U[2048 + (p >> 2) * 128 + lane * 4 + (p & 3)] = bl;
    }
    __syncthreads();
    // S3: 4 level-5 parents
    if (grp < 4) {
      const float tb = dot128(Wr, U + 2048 + grp * 128);
      const int lab = labs[1 + grp];
      float bl = tb * regB[lab * 33 + lane];
      bl /= rsum32(bl);
      U[2688 + (1 + grp) * 32 + lane] = tb;
      U[2560 + lane * 4 + grp] = bl;
    }
    __syncthreads();
    // S4: subtree root (level 4)
    if (grp == 0) {
      const float tb = dot128(Wr, U + 2560);
      const int lab = labs[0];
      float bl = tb * regB[lab * 33 + lane];
      bl /= rsum32(bl);
      U[2688 + lane] = tb;
      ws[OFF_B4 + s * 32 + lane] = bl;
    }
    __syncthreads();
    if (t == 0) {
      __threadfence();
      __hip_atomic_store(&wsi[OFF_FLAGSA + s], MAGIC, __ATOMIC_RELEASE,
                         __HIP_MEMORY_SCOPE_AGENT);
    }
  } else {
    // top: wait for all 256 level-4 betas (thread t spins on flag t)
    while (__hip_atomic_load(&wsi[OFF_FLAGSA + t], __ATOMIC_ACQUIRE,
                             __HIP_MEMORY_SCOPE_AGENT) != MAGIC)
      __builtin_amdgcn_s_sleep(2);
    __syncthreads();
    __threadfence();
    // U1: 64 level-3 parents, children = level-4 betas (staged via r_buf)
    for (int p = grp; p < 64; p += 8) {
#pragma unroll
      for (int l = 0; l < 4; ++l)
        r_buf[grp * 128 + lane * 4 + l] = ws[OFF_B4 + (p * 4 + l) * 32 + lane];
      const float tb = dot128(Wr, r_buf + grp * 128);
      const int lab = labs[21 + p];
      float bl = tb * regB[lab * 33 + lane];
      bl /= rsum32(bl);
      U[2720 + (21 + p) * 32 + lane] = tb;
      U[(p >> 2) * 128 + lane * 4 + (p & 3)] = bl;  // bX3
    }
    __syncthreads();
    // U2: 16 level-2 parents
    for (int p = grp; p < 16; p += 8) {
      const float tb = dot128(Wr, U + p * 128);
      const int lab = labs[5 + p];
      float bl = tb * regB[lab * 33 + lane];
      bl /= rsum32(bl);
      U[2720 + (5 + p) * 32 + lane] = tb;
      U[2048 + (p >> 2) * 128 + lane * 4 + (p & 3)] = bl;  // bX2
    }
    __syncthreads();
    // U3: 4 level-1 parents
    if (grp < 4) {
      const float tb = dot128(Wr, U + 2048 + grp * 128);
      const int lab = labs[1 + grp];
      float bl = tb * regB[lab * 33 + lane];
      bl /= rsum32(bl);
      U[2720 + (1 + grp) * 32 + lane] = tb;
      U[2560 + lane * 4 + grp] = bl;  // bX1
    }
    __syncthreads();
    // U4: root
    if (grp == 0) {
      const float tb = dot128(Wr, U + 2560);
      const int lab = labs[0];
      float bl = tb * regB[lab * 33 + lane];
      bl /= rsum32(bl);
      U[2720 + lane] = tb;
      U[2688 + lane] = bl;  // bRoot
    }
    __syncthreads();
  }

  // ---------- phase 3: transition to down tables (overlaps top's work) ----------
  for (int idx = t; idx < 4224; idx += 256) regB[idx] = logf(regB[idx]);
  if (t < 132) sPt[t] = logf(sPt[t]);
  // Wr -> down orientation (lane = j, Wr[i*4+l] = ASP[i,lane,l]); regW -> ALG.
#pragma unroll
  for (int i = 0; i < 32; ++i) {
    const float4 av = A4[i * 32 + lane];
    const float4 e = exp4(av);
    const float4 asp = make_float4(e.x * inv4.x, e.y * inv4.y, e.z * inv4.z, e.w * inv4.w);
    Wr[i * 4 + 0] = asp.x; Wr[i * 4 + 1] = asp.y;
    Wr[i * 4 + 2] = asp.z; Wr[i * 4 + 3] = asp.w;
    if (grp == (i >> 2))
      *(float4*)(regW + i * 128 + lane * 4) =
          make_float4(asp.x * (av.x - sub4.x), asp.y * (av.y - sub4.y),
                      asp.z * (av.z - sub4.z), asp.w * (av.w - sub4.w));
  }
  __syncthreads();

  // ---------- phase 4: down sweep ----------
  double ll = 0.0;
  if (top) {
    // D0: root
    if (grp == 0) {
      const float e0 = U[2688 + lane];
      ll += (double)(e0 * regB[labs[0] * 33 + lane]);
      const float r = e0 / U[2720 + lane];
      r_buf[lane] = r;
      float w[4], u[4];
      wu128(Wr, regW, r_buf, lane, w, u);
#pragma unroll
      for (int l = 0; l < 4; ++l) {
        const int cl = 1 + l;
        const float bc = U[2560 + lane * 4 + l];
        const float e = bc * w[l];
        ll += (double)(bc * u[l]);
        ll += (double)(e * regB[labs[cl] * 33 + lane]);
        U[2720 + cl * 32 + lane] = e / U[2720 + cl * 32 + lane];  // tb -> r
      }
    }
    __syncthreads();
    // D1: 4 level-1 parents
    if (grp < 4) {
      const int p = grp;
      const float r = U[2720 + (1 + p) * 32 + lane];
      r_buf[p * 32 + lane] = r;
      float w[4], u[4];
      wu128(Wr, regW, r_buf + p * 32, lane, w, u);
#pragma unroll
      for (int l = 0; l < 4; ++l) {
        const int cl = 5 + p * 4 + l;
        const float bc = U[2048 + p * 128 + lane * 4 + l];
        const float e = bc * w[l];
        ll += (double)(bc * u[l]);
        ll += (double)(e * regB[labs[cl] * 33 + lane]);
        U[2720 + cl * 32 + lane] = e / U[2720 + cl * 32 + lane];
      }
    }
    __syncthreads();
    // D2: 16 level-2 parents
    for (int p = grp; p < 16; p += 8) {
      const float r = U[2720 + (5 + p) * 32 + lane];
      float* rb = r_buf + ((p >> 3) & 1) * 256 + grp * 32;
      rb[lane] = r;
      float w[4], u[4];
      wu128(Wr, regW, rb, lane, w, u);
#pragma unroll
      for (int l = 0; l < 4; ++l) {
        const int cl = 21 + p * 4 + l;
        const float bc = U[p * 128 + lane * 4 + l];
        const float e = bc * w[l];
        ll += (double)(bc * u[l]);
        ll += (double)(e * regB[labs[cl] * 33 + lane]);
        U[2720 + cl * 32 + lane] = e / U[2720 + cl * 32 + lane];
      }
    }
    __syncthreads();
    // D3: 64 level-3 parents; children = level-4 (global) -> eps4 out
    for (int p = grp; p < 64; p += 8) {
      const float r = U[2720 + (21 + p) * 32 + lane];
      float* rb = r_buf + ((p >> 3) & 1) * 256 + grp * 32;
      rb[lane] = r;
      float w[4], u[4];
      wu128(Wr, regW, rb, lane, w, u);
#pragma unroll
      for (int l = 0; l < 4; ++l) {
        const int ci = p * 4 + l;
        const float bc = ws[OFF_B4 + ci * 32 + lane];
        const float e = bc * w[l];
        ws[OFF_EPS4 + ci * 32 + lane] = e;
        ll += (double)(bc * u[l]);
        ll += (double)(e * regB[labs[85 + ci] * 33 + lane]);
      }
    }
    __syncthreads();
    if (t == 0) {
      __threadfence();
      __hip_atomic_store(&wsi[OFF_FLAGB], MAGIC, __ATOMIC_RELEASE,
                         __HIP_MEMORY_SCOPE_AGENT);
    }
  } else {
    // wait for eps4
    if (t == 0) {
      while (__hip_atomic_load(&wsi[OFF_FLAGB], __ATOMIC_ACQUIRE,
                               __HIP_MEMORY_SCOPE_AGENT) != MAGIC)
        __builtin_amdgcn_s_sleep(2);
    }
    __syncthreads();
    __threadfence();
    // d0: subtree root (level 4)
    if (grp == 0) {
      const float r = ws[OFF_EPS4 + s * 32 + lane] / U[2688 + lane];
      r_buf[lane] = r;
      float w[4], u[4];
      wu128(Wr, regW, r_buf, lane, w, u);
#pragma unroll
      for (int l = 0; l < 4; ++l) {
        const int cl = 1 + l;  // L5 local id
        const float bc = U[2560 + lane * 4 + l];
        const float e = bc * w[l];
        ll += (double)(bc * u[l]);
        ll += (double)(e * regB[labs[cl] * 33 + lane]);
        U[2688 + cl * 32 + lane] = e / U[2688 + cl * 32 + lane];  // tb -> r
      }
    }
    __syncthreads();
    // d1: 4 level-5 parents
    if (grp < 4) {
      const int p = grp;
      const float r = U[2688 + (1 + p) * 32 + lane];
      r_buf[p * 32 + lane] = r;
      float w[4], u[4];
      wu128(Wr, regW, r_buf + p * 32, lane, w, u);
#pragma unroll
      for (int l = 0; l < 4; ++l) {
        const int q = p * 4 + l;  // L6 index
        const float bc = U[2048 + p * 128 + lane * 4 + l];
        const float e = bc * w[l];
        ll += (double)(bc * u[l]);
        ll += (double)(e * regB[labs[5 + q] * 33 + lane]);
        U[2688 + (5 + q) * 32 + lane] = e / U[2688 + (5 + q) * 32 + lane];
      }
    }
    __syncthreads();
    // d2: 16 level-6 parents; children = leaves
    for (int p = grp; p < 16; p += 8) {
      const float r = U[2688 + (5 + p) * 32 + lane];
      float* rb = r_buf + ((p >> 3) & 1) * 256 + grp * 32;
      rb[lane] = r;
      float w[4], u[4];
      wu128(Wr, regW, rb, lane, w, u);
#pragma unroll
      for (int l = 0; l < 4; ++l) {
        const int q = p * 4 + l;  // leaf index
        const float bc = U[p * 128 + lane * 4 + l];
        const float e = bc * w[l];
        ll += (double)(bc * u[l]);
        ll += (double)(e * regB[labs[21 + q] * 33 + lane]);
        ll += (double)(e * sPt[l * 33 + lane]);  // leaf_pos == l
      }
    }
  }

  // ---------- phase 5: reduction + finalize (R4-proven atomic pattern) ----------
#pragma unroll
  for (int k = 32; k >= 1; k >>= 1) ll += __shfl_xor(ll, k);
  double* rbd = (double*)r_buf;
  __syncthreads();
  if ((t & 63) == 0) rbd[t >> 6] = ll;
  __syncthreads();
  if (t == 0) {
    const double bsum = (rbd[0] + rbd[1]) + (rbd[2] + rbd[3]);
    atomicAdd((double*)(ws + OFF_ACC), bsum);
    __threadfence();
    const int old = atomicAdd(&wsi[OFF_DONE], 1);
    if (old == 256) {  // last of 257 blocks
      const double v = atomicAdd((double*)(ws + OFF_ACC), 0.0);
      out[0] = (float)v;
    }
  }
}

extern "C" void kernel_launch(void* const* d_in, const int* in_sizes, int n_in,
                              void* d_out, int out_size, void* d_ws, size_t ws_size,
                              hipStream_t stream) {
  (void)in_sizes; (void)n_in; (void)out_size; (void)ws_size;
  const int* labels = (const int*)d_in[0];
  const float* A = (const float*)d_in[1];
  const float* B = (const float*)d_in[2];
  const float* Pi = (const float*)d_in[3];
  const float* SP = (const float*)d_in[4];
  float* ws = (float*)d_ws;
  float* out = (float*)d_out;

  hipLaunchKernelGGL(k_fused, dim3(257), dim3(256), 0, stream,
                     labels, A, B, Pi, SP, ws, out);
}

// Round 7
// 145.365 us; speedup vs baseline: 3.4533x; 3.4533x over previous
//
#include <hip/hip_runtime.h>

// HTMM: C=32 states, L=4 fanout, M=128 symbols, DEPTH=7.
// Level starts: {0,1,5,21,85,341,1365,5461,21845}.
// SINGLE kernel, 256 blocks x 256 threads, one block per level-4 subtree.
// Grid barrier after each block publishes its level-4 beta (256 blocks <= 256
// CUs => all co-resident even at 1 block/CU; launch_bounds(256,1) = the only
// proven no-spill shape for Wr[128]).  Every block then redundantly computes
// the top-tree up-sweep from the 256 published betas; block 0 alone runs the
// full top-down (and adds top ll terms); every block walks its own 4-step
// path down to get its level-4 eps, then does its subtree down-sweep from
// LDS.  Down-pass child betas are recomputed from stored t_betas
// (beta = norm(tb*exp(logB))) so no beta arrays are kept -> LDS ~51 KB.

static constexpr int OFF_B4   = 0;      // level-4 betas [s*32+i] (8192 f)
static constexpr int OFF_ACC  = 8192;   // fp64 accumulator (2 f, 8B-aligned)
static constexpr int OFF_CNT1 = 8194;   // arrive counter (memset to 0)
static constexpr int OFF_CNT2 = 8195;   // done counter   (memset to 0)

__device__ __forceinline__ float rsum32(float v) {
  v += __shfl_xor(v, 1);
  v += __shfl_xor(v, 2);
  v += __shfl_xor(v, 4);
  v += __shfl_xor(v, 8);
  v += __shfl_xor(v, 16);
  return v;
}
__device__ __forceinline__ float4 exp4f(float4 v) {
  return make_float4(__expf(v.x), __expf(v.y), __expf(v.z), __expf(v.w));
}

// tb = sum_k Wr[k]*X[k], k=0..127; X read as uniform-address float4.
__device__ __forceinline__ float dot128(const float* Wr, const float* X) {
  float t0 = 0.f, t1 = 0.f, t2 = 0.f, t3 = 0.f;
#pragma unroll
  for (int j = 0; j < 32; ++j) {
    const float4 xv = *(const float4*)(X + j * 4);
    t0 = fmaf(Wr[j * 4 + 0], xv.x, t0);
    t1 = fmaf(Wr[j * 4 + 1], xv.y, t1);
    t2 = fmaf(Wr[j * 4 + 2], xv.z, t2);
    t3 = fmaf(Wr[j * 4 + 3], xv.w, t3);
  }
  return (t0 + t1) + (t2 + t3);
}

// w[l] = sum_i ASP[i,j=lane,l]*r[i] (Wr regs), u[l] = sum_i ALG[i,j=lane,l]*r[i].
__device__ __forceinline__ void wu128(const float* Wr, const float* ALG,
                                      const float* rb, int lane,
                                      float w[4], float u[4]) {
  w[0] = w[1] = w[2] = w[3] = 0.f;
  u[0] = u[1] = u[2] = u[3] = 0.f;
#pragma unroll
  for (int ii = 0; ii < 32; ii += 4) {
    const float4 rv = *(const float4*)(rb + ii);
#pragma unroll
    for (int di = 0; di < 4; ++di) {
      const int i = ii + di;
      const float rr = (di == 0) ? rv.x : (di == 1) ? rv.y : (di == 2) ? rv.z : rv.w;
      const float4 av = *(const float4*)(ALG + i * 128 + lane * 4);
      w[0] = fmaf(Wr[i * 4 + 0], rr, w[0]);
      u[0] = fmaf(av.x, rr, u[0]);
      w[1] = fmaf(Wr[i * 4 + 1], rr, w[1]);
      u[1] = fmaf(av.y, rr, u[1]);
      w[2] = fmaf(Wr[i * 4 + 2], rr, w[2]);
      u[2] = fmaf(av.z, rr, u[2]);
      w[3] = fmaf(Wr[i * 4 + 3], rr, w[3]);
      u[3] = fmaf(av.w, rr, u[3]);
    }
  }
}

// w-only variant (path walk: ll terms not needed).
__device__ __forceinline__ void wonly128(const float* Wr, const float* rb,
                                         float w[4]) {
  w[0] = w[1] = w[2] = w[3] = 0.f;
#pragma unroll
  for (int ii = 0; ii < 32; ii += 4) {
    const float4 rv = *(const float4*)(rb + ii);
#pragma unroll
    for (int di = 0; di < 4; ++di) {
      const int i = ii + di;
      const float rr = (di == 0) ? rv.x : (di == 1) ? rv.y : (di == 2) ? rv.z : rv.w;
      w[0] = fmaf(Wr[i * 4 + 0], rr, w[0]);
      w[1] = fmaf(Wr[i * 4 + 1], rr, w[1]);
      w[2] = fmaf(Wr[i * 4 + 2], rr, w[2]);
      w[3] = fmaf(Wr[i * 4 + 3], rr, w[3]);
    }
  }
}

__global__ __launch_bounds__(256, 1) void k_fused(const int* __restrict__ labels,
                                                  const float* __restrict__ A,
                                                  const float* __restrict__ B,
                                                  const float* __restrict__ Pi,
                                                  const float* __restrict__ SP,
                                                  float* __restrict__ ws,
                                                  float* __restrict__ out) {
  // LDS (floats):
  //  scr[4224] : phase A: asp up-layout [i*132+4j+l]
  //              subtree-up: X7[0,2048) X6[2048,2560) X5[2560,2688)
  //              top-up: stage[0,1024) bX3[2048,4096) bX2[1024,1536) bX1[1536,1664)
  //              down: ALG [i*128+4j+l] in [0,4096)
  //  regB[4224]: smB^T [m*33+i] -> logged in place at transition
  //  sPt[132]  : smPi^T [l*33+i] -> logged in place
  //  tbrT[2720]: top t_beta (85x32) -> r in place (block 0)
  //  tbS[672]  : subtree t_beta (local 0=L4,1..4=L5,5..20=L6) -> r in place
  //  ownb[32]  : own level-4 beta ; r_buf[256] : per-group r broadcast
  __shared__ __align__(16) float scr[4224];
  __shared__ __align__(16) float regB[4224];
  __shared__ __align__(16) float sPt[132];
  __shared__ __align__(16) float tbrT[2720];
  __shared__ __align__(16) float tbS[672];
  __shared__ __align__(16) float ownb[32];
  __shared__ __align__(16) float r_buf[256];
  __shared__ int labs[425];  // [0,341) top; [341,345) L5; [345,361) L6; [361,425) leaves
  const int t = threadIdx.x, lane = t & 31, grp = t >> 5;  // 8 groups
  const int s = blockIdx.x;
  int* wsi = (int*)ws;
  const float4* A4 = (const float4*)A;
  const float4* B4 = (const float4*)B;

  // ---------- phase 1: softmax tables ----------
  const float sv0 = SP[0], sv1 = SP[1], sv2 = SP[2], sv3 = SP[3];
  const float sp0 = __expf(sv0), sp1 = __expf(sv1), sp2 = __expf(sv2), sp3 = __expf(sv3);
  const float spsum = sp0 + sp1 + sp2 + sp3;
  const float spinv = 1.f / spsum;
  const float lss = __logf(spsum);
  float4 c4 = make_float4(0.f, 0.f, 0.f, 0.f);
  for (int i = 0; i < 32; ++i) {  // lane owns columns 4*lane..+3 (coalesced)
    const float4 e = exp4f(A4[i * 32 + lane]);
    c4.x += e.x; c4.y += e.y; c4.z += e.z; c4.w += e.w;
  }
  const float4 inv4 = make_float4(sp0 * spinv / c4.x, sp1 * spinv / c4.y,
                                  sp2 * spinv / c4.z, sp3 * spinv / c4.w);
  const float4 sub4 = make_float4(__logf(c4.x) - (sv0 - lss), __logf(c4.y) - (sv1 - lss),
                                  __logf(c4.z) - (sv2 - lss), __logf(c4.w) - (sv3 - lss));
#pragma unroll
  for (int k = 0; k < 4; ++k) {  // asp table (up layout, stride 132)
    const int i = grp * 4 + k;
    const float4 e = exp4f(A4[i * 32 + lane]);
    *(float4*)(scr + i * 132 + 4 * lane) =
        make_float4(e.x * inv4.x, e.y * inv4.y, e.z * inv4.z, e.w * inv4.w);
  }
#pragma unroll
  for (int rI = 0; rI < 4; ++rI) {  // smB^T
    const int i = grp + rI * 8;
    const float4 e = exp4f(B4[i * 32 + lane]);
    const float sinv = 1.f / rsum32(e.x + e.y + e.z + e.w);
    regB[(4 * lane + 0) * 33 + i] = e.x * sinv;
    regB[(4 * lane + 1) * 33 + i] = e.y * sinv;
    regB[(4 * lane + 2) * 33 + i] = e.z * sinv;
    regB[(4 * lane + 3) * 33 + i] = e.w * sinv;
  }
  if (grp < 4) {  // smPi^T
    const float e = __expf(Pi[lane * 4 + grp]);
    sPt[grp * 33 + lane] = e / rsum32(e);
  }
  for (int idx = t; idx < 341; idx += 256) labs[idx] = labels[idx];
  if (t < 84) {
    int g, d;
    if (t < 4) { g = 341 + 4 * s + t; d = 341 + t; }
    else if (t < 20) { g = 1365 + 16 * s + (t - 4); d = 345 + (t - 4); }
    else { g = 5461 + 64 * s + (t - 20); d = 361 + (t - 20); }
    labs[d] = labels[g];
  }
  __syncthreads();
  float Wr[128];  // up orientation: lane = state i; Wr[4j+l] = ASP[i,j,l]
#pragma unroll
  for (int j = 0; j < 32; ++j) {
    const float4 v = *(const float4*)(scr + lane * 132 + j * 4);
    Wr[4 * j] = v.x; Wr[4 * j + 1] = v.y; Wr[4 * j + 2] = v.z; Wr[4 * j + 3] = v.w;
  }
  __syncthreads();  // scr table consumed; region reusable

  // ---------- phase 2: subtree up sweep ----------
  for (int q = grp; q < 64; q += 8) {  // S1: leaves -> X7
    const int lab = labs[361 + q], l = q & 3;
    float v = sPt[l * 33 + lane] * regB[lab * 33 + lane];
    v /= rsum32(v);
    scr[(q >> 2) * 128 + lane * 4 + l] = v;
  }
  __syncthreads();
  for (int p = grp; p < 16; p += 8) {  // S2: L6 parents
    const float tb = dot128(Wr, scr + p * 128);
    const int lab = labs[345 + p];
    float bl = tb * regB[lab * 33 + lane];
    bl /= rsum32(bl);
    tbS[(5 + p) * 32 + lane] = tb;
    scr[2048 + (p >> 2) * 128 + lane * 4 + (p & 3)] = bl;  // X6
  }
  __syncthreads();
  if (grp < 4) {  // S3: L5 parents
    const float tb = dot128(Wr, scr + 2048 + grp * 128);
    const int lab = labs[341 + grp];
    float bl = tb * regB[lab * 33 + lane];
    bl /= rsum32(bl);
    tbS[(1 + grp) * 32 + lane] = tb;
    scr[2560 + lane * 4 + grp] = bl;  // X5
  }
  __syncthreads();
  if (grp == 0) {  // S4: own level-4 root
    const float tb = dot128(Wr, scr + 2560);
    const int lab = labs[85 + s];
    float bl = tb * regB[lab * 33 + lane];
    bl /= rsum32(bl);
    tbS[lane] = tb;
    ownb[lane] = bl;
    ws[OFF_B4 + s * 32 + lane] = bl;
  }
  __syncthreads();

  // ---------- grid barrier (all 256 blocks co-resident) ----------
  if (t == 0) {
    __threadfence();
    atomicAdd(&wsi[OFF_CNT1], 1);
    while (__hip_atomic_load(&wsi[OFF_CNT1], __ATOMIC_ACQUIRE,
                             __HIP_MEMORY_SCOPE_AGENT) < 256)
      __builtin_amdgcn_s_sleep(1);
  }
  __syncthreads();
  __threadfence();

  // ---------- phase 3: top up sweep (redundant per block) ----------
  for (int p = grp; p < 64; p += 8) {  // L3 parents; children = global b4
#pragma unroll
    for (int l = 0; l < 4; ++l)
      scr[grp * 128 + lane * 4 + l] = ws[OFF_B4 + (p * 4 + l) * 32 + lane];
    const float tb = dot128(Wr, scr + grp * 128);
    const int lab = labs[21 + p];
    float bl = tb * regB[lab * 33 + lane];
    bl /= rsum32(bl);
    tbrT[(21 + p) * 32 + lane] = tb;
    scr[2048 + (p >> 2) * 128 + lane * 4 + (p & 3)] = bl;  // bX3
  }
  __syncthreads();
  for (int p = grp; p < 16; p += 8) {  // L2 parents
    const float tb = dot128(Wr, scr + 2048 + p * 128);
    const int lab = labs[5 + p];
    float bl = tb * regB[lab * 33 + lane];
    bl /= rsum32(bl);
    tbrT[(5 + p) * 32 + lane] = tb;
    scr[1024 + (p >> 2) * 128 + lane * 4 + (p & 3)] = bl;  // bX2
  }
  __syncthreads();
  if (grp < 4) {  // L1 parents
    const float tb = dot128(Wr, scr + 1024 + grp * 128);
    const int lab = labs[1 + grp];
    float bl = tb * regB[lab * 33 + lane];
    bl /= rsum32(bl);
    tbrT[(1 + grp) * 32 + lane] = tb;
    scr[1536 + lane * 4 + grp] = bl;  // bX1
  }
  __syncthreads();
  if (grp == 0) {  // root (beta recomputed later from tb)
    tbrT[lane] = dot128(Wr, scr + 1536);
  }
  __syncthreads();

  // ---------- phase 4: transition to down tables ----------
  for (int idx = t; idx < 4224; idx += 256) regB[idx] = __logf(regB[idx]);
  if (t < 132) sPt[t] = __logf(sPt[t]);
#pragma unroll
  for (int i = 0; i < 32; ++i) {  // Wr -> down orient (lane=j); scr -> ALG
    const float4 av = A4[i * 32 + lane];
    const float4 e = exp4f(av);
    const float4 asp = make_float4(e.x * inv4.x, e.y * inv4.y, e.z * inv4.z, e.w * inv4.w);
    Wr[i * 4 + 0] = asp.x; Wr[i * 4 + 1] = asp.y;
    Wr[i * 4 + 2] = asp.z; Wr[i * 4 + 3] = asp.w;
    if (grp == (i >> 2))
      *(float4*)(scr + i * 128 + lane * 4) =
          make_float4(asp.x * (av.x - sub4.x), asp.y * (av.y - sub4.y),
                      asp.z * (av.z - sub4.z), asp.w * (av.w - sub4.w));
  }
  __syncthreads();

  // ---------- phase 5: top down ----------
  double ll = 0.0;
  float eps4own = 0.f;  // valid in grp 0
  if (s == 0) {
    // full top-down with ll (block 0 only)
    if (grp == 0) {  // D0: root
      const float tb0 = tbrT[lane];
      float bc = tb0 * __expf(regB[labs[0] * 33 + lane]);
      bc /= rsum32(bc);
      ll += (double)(bc * regB[labs[0] * 33 + lane]);  // eps_root*logB
      r_buf[lane] = bc / tb0;
      float w[4], u[4];
      wu128(Wr, scr, r_buf, lane, w, u);
#pragma unroll
      for (int l = 0; l < 4; ++l) {
        const int cl = 1 + l;
        const float tbv = tbrT[cl * 32 + lane];
        float bcv = tbv * __expf(regB[labs[cl] * 33 + lane]);
        bcv /= rsum32(bcv);
        const float e = bcv * w[l];
        ll += (double)(bcv * u[l]) + (double)(e * regB[labs[cl] * 33 + lane]);
        tbrT[cl * 32 + lane] = e / tbv;  // tb -> r
      }
    }
    __syncthreads();
    if (grp < 4) {  // D1: 4 L1 parents
      const int p = grp;
      r_buf[p * 32 + lane] = tbrT[(1 + p) * 32 + lane];
      float w[4], u[4];
      wu128(Wr, scr, r_buf + p * 32, lane, w, u);
#pragma unroll
      for (int l = 0; l < 4; ++l) {
        const int cl = 5 + p * 4 + l;
        const float tbv = tbrT[cl * 32 + lane];
        float bcv = tbv * __expf(regB[labs[cl] * 33 + lane]);
        bcv /= rsum32(bcv);
        const float e = bcv * w[l];
        ll += (double)(bcv * u[l]) + (double)(e * regB[labs[cl] * 33 + lane]);
        tbrT[cl * 32 + lane] = e / tbv;
      }
    }
    __syncthreads();
    for (int p = grp; p < 16; p += 8) {  // D2: 16 L2 parents
      r_buf[grp * 32 + lane] = tbrT[(5 + p) * 32 + lane];
      float w[4], u[4];
      wu128(Wr, scr, r_buf + grp * 32, lane, w, u);
#pragma unroll
      for (int l = 0; l < 4; ++l) {
        const int cl = 21 + p * 4 + l;
        const float tbv = tbrT[cl * 32 + lane];
        float bcv = tbv * __expf(regB[labs[cl] * 33 + lane]);
        bcv /= rsum32(bcv);
        const float e = bcv * w[l];
        ll += (double)(bcv * u[l]) + (double)(e * regB[labs[cl] * 33 + lane]);
        tbrT[cl * 32 + lane] = e / tbv;
      }
    }
    __syncthreads();
    for (int p = grp; p < 64; p += 8) {  // D3: 64 L3 parents; children = b4
      r_buf[grp * 32 + lane] = tbrT[(21 + p) * 32 + lane];
      float w[4], u[4];
      wu128(Wr, scr, r_buf + grp * 32, lane, w, u);
#pragma unroll
      for (int l = 0; l < 4; ++l) {
        const int ci = p * 4 + l;
        const float bcv = ws[OFF_B4 + ci * 32 + lane];
        const float e = bcv * w[l];
        ll += (double)(bcv * u[l]) + (double)(e * regB[labs[85 + ci] * 33 + lane]);
        if (ci == 0) eps4own = e;  // own (s=0) level-4 eps, grp 0
      }
    }
    __syncthreads();
  } else {
    // path-only walk (all groups redundantly; no ll, no tbrT writes)
    const int n1 = 1 + (s >> 6), n2 = 5 + (s >> 4), n3 = 21 + (s >> 2);
    const int a0 = s >> 6, a1 = (s >> 4) & 3, a2 = (s >> 2) & 3, a3 = s & 3;
    float w[4];
    float tbv = tbrT[lane];
    float bcv = tbv * __expf(regB[labs[0] * 33 + lane]);
    bcv /= rsum32(bcv);
    float r = bcv / tbv;
    r_buf[grp * 32 + lane] = r;
    wonly128(Wr, r_buf + grp * 32, w);
    tbv = tbrT[n1 * 32 + lane];
    bcv = tbv * __expf(regB[labs[n1] * 33 + lane]);
    bcv /= rsum32(bcv);
    r = (bcv * w[a0]) / tbv;
    r_buf[grp * 32 + lane] = r;
    wonly128(Wr, r_buf + grp * 32, w);
    tbv = tbrT[n2 * 32 + lane];
    bcv = tbv * __expf(regB[labs[n2] * 33 + lane]);
    bcv /= rsum32(bcv);
    r = (bcv * w[a1]) / tbv;
    r_buf[grp * 32 + lane] = r;
    wonly128(Wr, r_buf + grp * 32, w);
    tbv = tbrT[n3 * 32 + lane];
    bcv = tbv * __expf(regB[labs[n3] * 33 + lane]);
    bcv /= rsum32(bcv);
    r = (bcv * w[a2]) / tbv;
    r_buf[grp * 32 + lane] = r;
    wonly128(Wr, r_buf + grp * 32, w);
    eps4own = ownb[lane] * w[a3];
    __syncthreads();
  }

  // ---------- phase 6: subtree down sweep ----------
  if (grp == 0) {  // d0: own L4 node -> L5 children
    r_buf[lane] = eps4own / tbS[lane];
    float w[4], u[4];
    wu128(Wr, scr, r_buf, lane, w, u);
#pragma unroll
    for (int l = 0; l < 4; ++l) {
      const int lab = labs[341 + l];
      const float tbv = tbS[(1 + l) * 32 + lane];
      float bcv = tbv * __expf(regB[lab * 33 + lane]);
      bcv /= rsum32(bcv);
      const float e = bcv * w[l];
      ll += (double)(bcv * u[l]) + (double)(e * regB[lab * 33 + lane]);
      tbS[(1 + l) * 32 + lane] = e / tbv;
    }
  }
  __syncthreads();
  if (grp < 4) {  // d1: 4 L5 parents -> L6 children
    const int p = grp;
    r_buf[p * 32 + lane] = tbS[(1 + p) * 32 + lane];
    float w[4], u[4];
    wu128(Wr, scr, r_buf + p * 32, lane, w, u);
#pragma unroll
    for (int l = 0; l < 4; ++l) {
      const int q = p * 4 + l;
      const int lab = labs[345 + q];
      const float tbv = tbS[(5 + q) * 32 + lane];
      float bcv = tbv * __expf(regB[lab * 33 + lane]);
      bcv /= rsum32(bcv);
      const float e = bcv * w[l];
      ll += (double)(bcv * u[l]) + (double)(e * regB[lab * 33 + lane]);
      tbS[(5 + q) * 32 + lane] = e / tbv;
    }
  }
  __syncthreads();
  for (int p = grp; p < 16; p += 8) {  // d2: 16 L6 parents -> leaves
    r_buf[grp * 32 + lane] = tbS[(5 + p) * 32 + lane];
    float w[4], u[4];
    wu128(Wr, scr, r_buf + grp * 32, lane, w, u);
#pragma unroll
    for (int l = 0; l < 4; ++l) {
      const int q = p * 4 + l;
      const int lab = labs[361 + q];
      float bcv = __expf(sPt[l * 33 + lane] + regB[lab * 33 + lane]);
      bcv /= rsum32(bcv);
      const float e = bcv * w[l];
      ll += (double)(bcv * u[l]) + (double)(e * regB[lab * 33 + lane]) +
            (double)(e * sPt[l * 33 + lane]);  // leaf_pos == l
    }
  }

  // ---------- phase 7: reduction + finalize ----------
#pragma unroll
  for (int k = 32; k >= 1; k >>= 1) ll += __shfl_xor(ll, k);
  double* rbd = (double*)r_buf;
  __syncthreads();
  if ((t & 63) == 0) rbd[t >> 6] = ll;
  __syncthreads();
  if (t == 0) {
    const double bsum = (rbd[0] + rbd[1]) + (rbd[2] + rbd[3]);
    atomicAdd((double*)(ws + OFF_ACC), bsum);
    __threadfence();
    const int old = atomicAdd(&wsi[OFF_CNT2], 1);
    if (old == 255) {
      const double v = atomicAdd((double*)(ws + OFF_ACC), 0.0);
      out[0] = (float)v;
    }
  }
}

extern "C" void kernel_launch(void* const* d_in, const int* in_sizes, int n_in,
                              void* d_out, int out_size, void* d_ws, size_t ws_size,
                              hipStream_t stream) {
  (void)in_sizes; (void)n_in; (void)out_size; (void)ws_size;
  const int* labels = (const int*)d_in[0];
  const float* A = (const float*)d_in[1];
  const float* B = (const float*)d_in[2];
  const float* Pi = (const float*)d_in[3];
  const float* SP = (const float*)d_in[4];
  float* ws = (float*)d_ws;
  float* out = (float*)d_out;

  // zero ACC (8 B) + CNT1 + CNT2 (8 B) at float offset 8192
  hipMemsetAsync((char*)d_ws + 8192 * sizeof(float), 0, 16, stream);
  hipLaunchKernelGGL(k_fused, dim3(256), dim3(256), 0, stream,
                     labels, A, B, Pi, SP, ws, out);
}